// Round 6
// baseline (669.795 us; speedup 1.0000x reference)
//
#include <hip/hip_runtime.h>
#include <math.h>

#define N_NODES 60000
#define N_EDGES 600000
#define B_GRAPHS 512
#define DIM 128
#define RBF_R 30
#define NLAYERS 3
#define NBINS 1024
#define CHUNK 512
#define NCHUNK ((N_NODES + CHUNK - 1) / CHUNK)   // 118

typedef __attribute__((ext_vector_type(8))) short bf16x8;
typedef __attribute__((ext_vector_type(4))) float f32x4;

__device__ __forceinline__ float sp05(float x) {
    float bx = 0.5f * x;
    return bx > 14.0f ? x : 2.0f * log1pf(expf(bx));
}
__device__ __forceinline__ float sp1(float x) {
    return x > 20.0f ? x : log1pf(expf(x));
}
__device__ __forceinline__ unsigned short f2bf(float f) {
    unsigned int u = __float_as_uint(f);
    unsigned int r = u + 0x7FFFu + ((u >> 16) & 1u);  // RNE
    return (unsigned short)(r >> 16);
}
__device__ __forceinline__ float bf2f(unsigned int s) {
    return __uint_as_float(s << 16);
}

// ---------------- one-time conversion kernels ----------------
// Fragment-order layout: each MFMA B-fragment (64 lanes x 16B = 512 bf16) is
// stored contiguously so the per-wave bfrag load is ONE coalesced 1KB read.

__global__ void k_convW(const float* __restrict__ Wn1, const float* __restrict__ Wn2,
                        const float* __restrict__ Wn3, unsigned short* __restrict__ WtF) {
    int i = blockIdx.x * 256 + threadIdx.x;              // 9*16384
    int mat = i >> 14, r = i & 16383;
    int frag = r >> 9, within = r & 511;
    int ks = frag >> 3, ntile = frag & 7;
    int lane = within >> 3, j = within & 7;
    int q = lane >> 4, l16 = lane & 15;
    int n = ntile * 16 + l16;
    int k = ks * 32 + q * 8 + j;
    const float* src = (mat < 3) ? (Wn1 + (size_t)mat * 16384)
                     : (mat < 6) ? (Wn2 + (size_t)(mat - 3) * 16384)
                                 : (Wn3 + (size_t)(mat - 6) * 16384);
    WtF[i] = f2bf(src[k * 128 + n]);
}

// Wr1 [512][64] -> fragment order: frag=(lvl,ks,ntile) 4*4*4=64 frags of 512.
__global__ void k_convR(const float* __restrict__ Wr1, unsigned short* __restrict__ Wr1tF) {
    int i = blockIdx.x * 256 + threadIdx.x;              // 32768
    int frag = i >> 9, within = i & 511;
    int lvl = frag >> 4, ks = (frag >> 2) & 3, ntile = frag & 3;
    int lane = within >> 3, j = within & 7;
    int q = lane >> 4, l16 = lane & 15;
    int n = ntile * 16 + l16;
    int k = lvl * 128 + ks * 32 + q * 8 + j;
    Wr1tF[i] = f2bf(Wr1[k * 64 + n]);
}

// h0 = node_emb[atom_type] (fp32 + bf16 copies)
__global__ void k_embed(const int* __restrict__ atom_type,
                        const float* __restrict__ node_emb,
                        float* __restrict__ h0, unsigned short* __restrict__ hb0) {
    int i = blockIdx.x * blockDim.x + threadIdx.x;
    if (i >= N_NODES * DIM) return;
    int n = i >> 7, d = i & 127;
    float v = node_emb[atom_type[n] * DIM + d];
    h0[i] = v;
    hb0[i] = f2bf(v);
}

// ---------------- CSR build (once per call) ----------------

__global__ void k_hist(const int* __restrict__ dst, int* __restrict__ counts) {
    int e = blockIdx.x * blockDim.x + threadIdx.x;
    if (e >= N_EDGES) return;
    atomicAdd(&counts[dst[e]], 1);
}

__global__ void k_bsum(const int* __restrict__ counts, int* __restrict__ bsums) {
    __shared__ int red[256];
    int c = blockIdx.x, tid = threadIdx.x;
    int base = c * CHUNK;
    int v = 0;
    for (int i = tid; i < CHUNK; i += 256)
        if (base + i < N_NODES) v += counts[base + i];
    red[tid] = v;
    __syncthreads();
    for (int s = 128; s > 0; s >>= 1) {
        if (tid < s) red[tid] += red[tid + s];
        __syncthreads();
    }
    if (tid == 0) bsums[c] = red[0];
}

__global__ void k_scan_b(int* __restrict__ bsums) {
    __shared__ int sb[NCHUNK];
    int tid = threadIdx.x;
    if (tid < NCHUNK) sb[tid] = bsums[tid];
    __syncthreads();
    if (tid == 0) {
        int run = 0;
        for (int i = 0; i < NCHUNK; ++i) { int v = sb[i]; sb[i] = run; run += v; }
    }
    __syncthreads();
    if (tid < NCHUNK) bsums[tid] = sb[tid];
}

__global__ void k_scan_final(const int* __restrict__ counts, const int* __restrict__ bsums,
                             int* __restrict__ offsets) {
    __shared__ int sc[CHUNK];
    int c = blockIdx.x, tid = threadIdx.x;
    int base = c * CHUNK;
    for (int i = tid; i < CHUNK; i += 256)
        sc[i] = (base + i < N_NODES) ? counts[base + i] : 0;
    __syncthreads();
    if (tid == 0) {
        int run = bsums[c];
        for (int i = 0; i < CHUNK; ++i) { int v = sc[i]; sc[i] = run; run += v; }
    }
    __syncthreads();
    for (int i = tid; i < CHUNK; i += 256)
        if (base + i < N_NODES) offsets[base + i] = sc[i];
    if (c == 0 && tid == 0) offsets[N_NODES] = N_EDGES;
}

__global__ void k_fill(const int* __restrict__ src, const int* __restrict__ dst,
                       const float* __restrict__ dist,
                       const int* __restrict__ offsets, int* __restrict__ cnt2,
                       int* __restrict__ srcp, int* __restrict__ binp,
                       float* __restrict__ wp) {
    int e = blockIdx.x * blockDim.x + threadIdx.x;
    if (e >= N_EDGES) return;
    int d = dst[e];
    int pos = offsets[d] + atomicAdd(&cnt2[d], 1);
    srcp[pos] = src[e];
    float x = dist[e];
    float p = x * ((float)NBINS / 10.0f);
    int bin = (int)p;
    if (bin > NBINS - 1) bin = NBINS - 1;
    binp[pos] = bin;
    wp[pos] = p - (float)bin;
}

// ---------------- per-layer kernels ----------------

// Tabulate edge MLP on NBINS+1 bins -> bf16 table.
__global__ void k_table(const float* __restrict__ Wc1, const float* __restrict__ bc1,
                        const float* __restrict__ Wc2, const float* __restrict__ bc2,
                        const float* __restrict__ Wc3, const float* __restrict__ bc3,
                        unsigned short* __restrict__ tableb) {
    __shared__ float t[DIM];
    __shared__ float u[DIM];
    int b = blockIdx.x;
    int d = threadIdx.x;
    float dist = (float)b * (10.0f / (float)NBINS);
    const float gap = 10.0f / 29.0f;
    float acc = bc1[d];
#pragma unroll
    for (int k = 0; k < RBF_R; ++k) {
        float c = (float)k * (10.0f / 29.0f);
        float df = dist - c;
        acc += expf(-df * df / gap) * Wc1[k * DIM + d];
    }
    t[d] = sp05(acc);
    __syncthreads();
    acc = bc2[d];
#pragma unroll 8
    for (int k = 0; k < DIM; ++k) acc += t[k] * Wc2[k * DIM + d];
    u[d] = acc;
    __syncthreads();
    acc = bc3[d];
#pragma unroll 8
    for (int k = 0; k < DIM; ++k) acc += u[k] * Wc3[k * DIM + d];
    tableb[b * DIM + d] = f2bf(acc);
}

// Pack (a, delta) per bin/dim into one uint: lo=a, hi=table[bin+1]-table[bin].
__global__ void k_pack(const unsigned short* __restrict__ tableb,
                       unsigned int* __restrict__ packed) {
    int i = blockIdx.x * 256 + threadIdx.x;   // NBINS*128
    float a = bf2f(tableb[i]);
    float b = bf2f(tableb[i + DIM]);
    packed[i] = (unsigned int)f2bf(a) | ((unsigned int)f2bf(b - a) << 16);
}

// MFMA GEMM: Cb = bf16( Ab @ W^T + bias + 1 ). Fragment-order B.
__global__ __launch_bounds__(256) void k_gemm_g(const unsigned short* __restrict__ Ab,
                                                const unsigned short* __restrict__ WtF,
                                                const float* __restrict__ bias,
                                                unsigned short* __restrict__ Cb) {
    int tid = threadIdx.x;
    int wave = tid >> 6, lane = tid & 63;
    int q = lane >> 4, l16 = lane & 15;
    int mhalf = wave & 1, nhalf = wave >> 1;
    int rb = blockIdx.x * 64 + mhalf * 32;
    int c0 = nhalf * 64;
    bf16x8 bfrag[4][4];
#pragma unroll
    for (int ks = 0; ks < 4; ++ks)
#pragma unroll
        for (int nt = 0; nt < 4; ++nt)
            bfrag[ks][nt] = *(const bf16x8*)&WtF[(size_t)(ks * 8 + nhalf * 4 + nt) * 512 + lane * 8];
    f32x4 acc[2][4] = {};
#pragma unroll
    for (int ks = 0; ks < 4; ++ks)
#pragma unroll
        for (int mt = 0; mt < 2; ++mt) {
            int m = rb + mt * 16 + l16;
            if (m > N_NODES - 1) m = N_NODES - 1;
            bf16x8 a = *(const bf16x8*)&Ab[(size_t)m * 128 + ks * 32 + q * 8];
#pragma unroll
            for (int nt = 0; nt < 4; ++nt)
                acc[mt][nt] = __builtin_amdgcn_mfma_f32_16x16x32_bf16(a, bfrag[ks][nt], acc[mt][nt], 0, 0, 0);
        }
#pragma unroll
    for (int mt = 0; mt < 2; ++mt)
#pragma unroll
        for (int nt = 0; nt < 4; ++nt) {
            int col = c0 + nt * 16 + l16;
            float b = bias[col] + 1.0f;
#pragma unroll
            for (int r = 0; r < 4; ++r) {
                int row = rb + mt * 16 + q * 4 + r;
                if (row < N_NODES) Cb[(size_t)row * 128 + col] = f2bf(acc[mt][nt][r] + b);
            }
        }
}

// Gather: wave-per-node (4 nodes / 256-block). Lane owns dims {2*lane, 2*lane+1}.
// Per edge: 3 broadcast meta loads + one 8B packed-table load + one 4B g load.
__global__ __launch_bounds__(256) void k_gather(
    const int* __restrict__ offsets, const int* __restrict__ srcp,
    const int* __restrict__ binp, const float* __restrict__ wp,
    const unsigned int* __restrict__ packed, const unsigned short* __restrict__ gb,
    unsigned short* __restrict__ nodeb) {
    int wave = threadIdx.x >> 6, lane = threadIdx.x & 63;
    int n = blockIdx.x * 4 + wave;
    int beg = offsets[n], end = offsets[n + 1];
    float acc0 = 0.f, acc1 = 0.f, acc2 = 0.f, acc3 = 0.f;
    int j = beg;
    for (; j + 2 <= end; j += 2) {
        int s0 = srcp[j],   s1 = srcp[j + 1];
        int b0 = binp[j],   b1 = binp[j + 1];
        float w0 = wp[j],   w1 = wp[j + 1];
        uint2 p0 = *(const uint2*)&packed[(size_t)b0 * DIM + lane * 2];
        uint2 p1 = *(const uint2*)&packed[(size_t)b1 * DIM + lane * 2];
        unsigned int g0 = *(const unsigned int*)&gb[(size_t)s0 * DIM + lane * 2];
        unsigned int g1 = *(const unsigned int*)&gb[(size_t)s1 * DIM + lane * 2];
        acc0 += bf2f(g0 & 0xffff) * (bf2f(p0.x & 0xffff) + w0 * bf2f(p0.x >> 16));
        acc1 += bf2f(g0 >> 16)    * (bf2f(p0.y & 0xffff) + w0 * bf2f(p0.y >> 16));
        acc2 += bf2f(g1 & 0xffff) * (bf2f(p1.x & 0xffff) + w1 * bf2f(p1.x >> 16));
        acc3 += bf2f(g1 >> 16)    * (bf2f(p1.y & 0xffff) + w1 * bf2f(p1.y >> 16));
    }
    if (j < end) {
        int s0 = srcp[j];
        int b0 = binp[j];
        float w0 = wp[j];
        uint2 p0 = *(const uint2*)&packed[(size_t)b0 * DIM + lane * 2];
        unsigned int g0 = *(const unsigned int*)&gb[(size_t)s0 * DIM + lane * 2];
        acc0 += bf2f(g0 & 0xffff) * (bf2f(p0.x & 0xffff) + w0 * bf2f(p0.x >> 16));
        acc1 += bf2f(g0 >> 16)    * (bf2f(p0.y & 0xffff) + w0 * bf2f(p0.y >> 16));
    }
    acc0 += acc2; acc1 += acc3;
    unsigned int o = (unsigned int)f2bf(acc0) | ((unsigned int)f2bf(acc1) << 16);
    *(unsigned int*)&nodeb[(size_t)n * DIM + lane * 2] = o;
}

// h_out = h_in + sp05(nodeb@W2^T + b2) @ W3^T + b3 ; fp32 + bf16 outputs.
__global__ __launch_bounds__(256) void k_node_update(
    const unsigned short* __restrict__ nodeb,
    const unsigned short* __restrict__ W2tF, const float* __restrict__ b2,
    const unsigned short* __restrict__ W3tF, const float* __restrict__ b3,
    const float* __restrict__ h_in, float* __restrict__ h_out,
    unsigned short* __restrict__ hb_out) {
    __shared__ unsigned short ts[64][136];
    int tid = threadIdx.x;
    int wave = tid >> 6, lane = tid & 63;
    int q = lane >> 4, l16 = lane & 15;
    int mhalf = wave & 1, nhalf = wave >> 1;
    int rb = blockIdx.x * 64 + mhalf * 32;
    int c0 = nhalf * 64;

    bf16x8 bfrag[4][4];
#pragma unroll
    for (int ks = 0; ks < 4; ++ks)
#pragma unroll
        for (int nt = 0; nt < 4; ++nt)
            bfrag[ks][nt] = *(const bf16x8*)&W2tF[(size_t)(ks * 8 + nhalf * 4 + nt) * 512 + lane * 8];
    f32x4 acc[2][4] = {};
#pragma unroll
    for (int ks = 0; ks < 4; ++ks)
#pragma unroll
        for (int mt = 0; mt < 2; ++mt) {
            int m = rb + mt * 16 + l16;
            if (m > N_NODES - 1) m = N_NODES - 1;
            bf16x8 a = *(const bf16x8*)&nodeb[(size_t)m * 128 + ks * 32 + q * 8];
#pragma unroll
            for (int nt = 0; nt < 4; ++nt)
                acc[mt][nt] = __builtin_amdgcn_mfma_f32_16x16x32_bf16(a, bfrag[ks][nt], acc[mt][nt], 0, 0, 0);
        }
#pragma unroll
    for (int mt = 0; mt < 2; ++mt)
#pragma unroll
        for (int nt = 0; nt < 4; ++nt) {
            int col = c0 + nt * 16 + l16;
            float b = b2[col];
#pragma unroll
            for (int r = 0; r < 4; ++r) {
                int lrow = mhalf * 32 + mt * 16 + q * 4 + r;
                ts[lrow][col] = f2bf(sp05(acc[mt][nt][r] + b));
            }
        }
    __syncthreads();
#pragma unroll
    for (int ks = 0; ks < 4; ++ks)
#pragma unroll
        for (int nt = 0; nt < 4; ++nt)
            bfrag[ks][nt] = *(const bf16x8*)&W3tF[(size_t)(ks * 8 + nhalf * 4 + nt) * 512 + lane * 8];
#pragma unroll
    for (int mt = 0; mt < 2; ++mt)
#pragma unroll
        for (int nt = 0; nt < 4; ++nt) acc[mt][nt] = (f32x4){0.f, 0.f, 0.f, 0.f};
#pragma unroll
    for (int ks = 0; ks < 4; ++ks)
#pragma unroll
        for (int mt = 0; mt < 2; ++mt) {
            int lrow = mhalf * 32 + mt * 16 + l16;
            bf16x8 a = *(const bf16x8*)&ts[lrow][ks * 32 + q * 8];
#pragma unroll
            for (int nt = 0; nt < 4; ++nt)
                acc[mt][nt] = __builtin_amdgcn_mfma_f32_16x16x32_bf16(a, bfrag[ks][nt], acc[mt][nt], 0, 0, 0);
        }
#pragma unroll
    for (int mt = 0; mt < 2; ++mt)
#pragma unroll
        for (int nt = 0; nt < 4; ++nt) {
            int col = c0 + nt * 16 + l16;
            float b = b3[col];
#pragma unroll
            for (int r = 0; r < 4; ++r) {
                int row = rb + mt * 16 + q * 4 + r;
                if (row < N_NODES) {
                    size_t idx = (size_t)row * 128 + col;
                    float v = h_in[idx] + acc[mt][nt][r] + b;
                    h_out[idx] = v;
                    hb_out[idx] = f2bf(v);
                }
            }
        }
}

// Readout: 64 rows/block (1 m-tile per wave) for 2x grid parallelism.
__global__ __launch_bounds__(256) void k_readout(
    const unsigned short* __restrict__ hb0, const unsigned short* __restrict__ hb1,
    const unsigned short* __restrict__ hb2, const unsigned short* __restrict__ hb3,
    const unsigned short* __restrict__ Wr1tF, const float* __restrict__ br1,
    const float* __restrict__ Wr2, const float* __restrict__ br2,
    const int* __restrict__ graph_ids, float* __restrict__ out) {
    int tid = threadIdx.x;
    int wave = tid >> 6, lane = tid & 63;
    int q = lane >> 4, l16 = lane & 15;
    int rb = blockIdx.x * 64 + wave * 16;
    const unsigned short* hbs[4] = {hb0, hb1, hb2, hb3};
    f32x4 acc[4] = {};
    for (int lvl = 0; lvl < 4; ++lvl) {
        bf16x8 bfrag[4][4];
#pragma unroll
        for (int ks = 0; ks < 4; ++ks)
#pragma unroll
            for (int nt = 0; nt < 4; ++nt)
                bfrag[ks][nt] = *(const bf16x8*)&Wr1tF[(size_t)((lvl * 4 + ks) * 4 + nt) * 512 + lane * 8];
        const unsigned short* Ab = hbs[lvl];
#pragma unroll
        for (int ks = 0; ks < 4; ++ks) {
            int m = rb + l16;
            if (m > N_NODES - 1) m = N_NODES - 1;
            bf16x8 a = *(const bf16x8*)&Ab[(size_t)m * 128 + ks * 32 + q * 8];
#pragma unroll
            for (int nt = 0; nt < 4; ++nt)
                acc[nt] = __builtin_amdgcn_mfma_f32_16x16x32_bf16(a, bfrag[ks][nt], acc[nt], 0, 0, 0);
        }
    }
    float brr = br2[0];
    float partial[4] = {0.f, 0.f, 0.f, 0.f};
#pragma unroll
    for (int nt = 0; nt < 4; ++nt) {
        int col = nt * 16 + l16;
        float b = br1[col];
        float w = Wr2[col];
#pragma unroll
        for (int r = 0; r < 4; ++r) partial[r] += sp1(acc[nt][r] + b) * w;
    }
#pragma unroll
    for (int r = 0; r < 4; ++r) {
        float v = partial[r];
        v += __shfl_xor(v, 1); v += __shfl_xor(v, 2);
        v += __shfl_xor(v, 4); v += __shfl_xor(v, 8);
        if (l16 == 0) {
            int row = rb + q * 4 + r;
            if (row < N_NODES) atomicAdd(&out[graph_ids[row]], v + brr);
        }
    }
}

extern "C" void kernel_launch(void* const* d_in, const int* in_sizes, int n_in,
                              void* d_out, int out_size, void* d_ws, size_t ws_size,
                              hipStream_t stream) {
    const int* atom_type   = (const int*)d_in[0];
    const int* src         = (const int*)d_in[1];
    const int* dst         = (const int*)d_in[2];
    const int* graph_ids   = (const int*)d_in[3];
    const float* dist      = (const float*)d_in[4];
    const float* node_emb  = (const float*)d_in[5];
    const float* W_n1 = (const float*)d_in[6];  const float* b_n1 = (const float*)d_in[7];
    const float* W_c1 = (const float*)d_in[8];  const float* b_c1 = (const float*)d_in[9];
    const float* W_c2 = (const float*)d_in[10]; const float* b_c2 = (const float*)d_in[11];
    const float* W_c3 = (const float*)d_in[12]; const float* b_c3 = (const float*)d_in[13];
    const float* W_n2 = (const float*)d_in[14]; const float* b_n2 = (const float*)d_in[15];
    const float* W_n3 = (const float*)d_in[16]; const float* b_n3 = (const float*)d_in[17];
    const float* W_r1 = (const float*)d_in[18]; const float* b_r1 = (const float*)d_in[19];
    const float* W_r2 = (const float*)d_in[20]; const float* b_r2 = (const float*)d_in[21];
    float* out = (float*)d_out;

    size_t ND = (size_t)N_NODES * DIM;   // 7,680,000
    // float region
    float* h_even = (float*)d_ws;
    float* h_odd  = h_even + ND;
    float* wp     = h_odd + ND;                          // 600000
    // int region
    int* offsets  = (int*)(wp + N_EDGES);               // 60008 (padded)
    int* srcp     = offsets + 60008;                    // 600000
    int* binp     = srcp + N_EDGES;                     // 600000
    int* counts   = binp + N_EDGES;                     // 60000
    int* cnt2     = counts + N_NODES;                   // 60000
    int* bsums    = cnt2 + N_NODES;                     // 128 (padded)
    unsigned int* packed = (unsigned int*)(bsums + 128);  // NBINS*128 uints
    // ushort region
    unsigned short* hb0    = (unsigned short*)(packed + (size_t)NBINS * DIM);
    unsigned short* hb1    = hb0 + ND;
    unsigned short* hb2    = hb1 + ND;
    unsigned short* hb3    = hb2 + ND;
    unsigned short* gb     = hb3 + ND;
    unsigned short* nodeb  = gb + ND;
    unsigned short* tableb = nodeb + ND;                // (NBINS+1)*128
    unsigned short* WtF    = tableb + (size_t)(NBINS + 1) * DIM;  // 9*16384
    unsigned short* Wr1tF  = WtF + 9 * 16384;           // 32768

    unsigned short* hbp[4] = {hb0, hb1, hb2, hb3};
    float* hcur = h_even;
    float* hnext = h_odd;

    hipMemsetAsync(out, 0, B_GRAPHS * sizeof(float), stream);
    hipMemsetAsync(counts, 0, (2 * N_NODES + 128) * sizeof(int), stream);

    k_convW<<<(9 * 16384) / 256, 256, 0, stream>>>(W_n1, W_n2, W_n3, WtF);
    k_convR<<<32768 / 256, 256, 0, stream>>>(W_r1, Wr1tF);
    k_embed<<<(N_NODES * DIM) / 256, 256, 0, stream>>>(atom_type, node_emb, h_even, hb0);

    // CSR build (dst-sorted edge meta)
    k_hist<<<(N_EDGES + 255) / 256, 256, 0, stream>>>(dst, counts);
    k_bsum<<<NCHUNK, 256, 0, stream>>>(counts, bsums);
    k_scan_b<<<1, 128, 0, stream>>>(bsums);
    k_scan_final<<<NCHUNK, 256, 0, stream>>>(counts, bsums, offsets);
    k_fill<<<(N_EDGES + 255) / 256, 256, 0, stream>>>(src, dst, dist, offsets, cnt2,
                                                      srcp, binp, wp);

    int gblocks = (N_NODES + 63) / 64;      // 938
    for (int i = 0; i < NLAYERS; ++i) {
        k_table<<<NBINS + 1, DIM, 0, stream>>>(
            W_c1 + (size_t)i * RBF_R * DIM, b_c1 + (size_t)i * DIM,
            W_c2 + (size_t)i * DIM * DIM,  b_c2 + (size_t)i * DIM,
            W_c3 + (size_t)i * DIM * DIM,  b_c3 + (size_t)i * DIM, tableb);
        k_pack<<<(NBINS * DIM) / 256, 256, 0, stream>>>(tableb, packed);
        k_gemm_g<<<gblocks, 256, 0, stream>>>(
            hbp[i], WtF + (size_t)i * 16384, b_n1 + (size_t)i * DIM, gb);
        k_gather<<<N_NODES / 4, 256, 0, stream>>>(offsets, srcp, binp, wp, packed, gb, nodeb);
        k_node_update<<<gblocks, 256, 0, stream>>>(
            nodeb, WtF + (size_t)(3 + i) * 16384, b_n2 + (size_t)i * DIM,
            WtF + (size_t)(6 + i) * 16384, b_n3 + (size_t)i * DIM,
            hcur, hnext, hbp[i + 1]);
        float* tmp = hcur; hcur = hnext; hnext = tmp;
    }
    k_readout<<<gblocks, 256, 0, stream>>>(
        hb0, hb1, hb2, hb3, Wr1tF, b_r1, W_r2, b_r2, graph_ids, out);
}

// Round 7
// 640.737 us; speedup vs baseline: 1.0454x; 1.0454x over previous
//
#include <hip/hip_runtime.h>
#include <math.h>

#define N_NODES 60000
#define N_EDGES 600000
#define B_GRAPHS 512
#define DIM 128
#define RBF_R 30
#define NLAYERS 3
#define NBINS 1024
#define CHUNK 512
#define NCHUNK ((N_NODES + CHUNK - 1) / CHUNK)   // 118

typedef __attribute__((ext_vector_type(8))) short bf16x8;
typedef __attribute__((ext_vector_type(4))) float f32x4;

__device__ __forceinline__ float sp05(float x) {
    float bx = 0.5f * x;
    return bx > 14.0f ? x : 2.0f * log1pf(expf(bx));
}
__device__ __forceinline__ float sp1(float x) {
    return x > 20.0f ? x : log1pf(expf(x));
}
__device__ __forceinline__ unsigned short f2bf(float f) {
    unsigned int u = __float_as_uint(f);
    unsigned int r = u + 0x7FFFu + ((u >> 16) & 1u);  // RNE
    return (unsigned short)(r >> 16);
}
__device__ __forceinline__ float bf2f(unsigned int s) {
    return __uint_as_float(s << 16);
}

// ---------------- one-time conversion kernels ----------------
// Fragment-order layout: each MFMA B-fragment (64 lanes x 16B = 512 bf16) is
// stored contiguously so the per-wave bfrag load is ONE coalesced 1KB read.

__global__ void k_convW(const float* __restrict__ Wn1, const float* __restrict__ Wn2,
                        const float* __restrict__ Wn3, unsigned short* __restrict__ WtF) {
    int i = blockIdx.x * 256 + threadIdx.x;              // 9*16384
    int mat = i >> 14, r = i & 16383;
    int frag = r >> 9, within = r & 511;
    int ks = frag >> 3, ntile = frag & 7;
    int lane = within >> 3, j = within & 7;
    int q = lane >> 4, l16 = lane & 15;
    int n = ntile * 16 + l16;
    int k = ks * 32 + q * 8 + j;
    const float* src = (mat < 3) ? (Wn1 + (size_t)mat * 16384)
                     : (mat < 6) ? (Wn2 + (size_t)(mat - 3) * 16384)
                                 : (Wn3 + (size_t)(mat - 6) * 16384);
    WtF[i] = f2bf(src[k * 128 + n]);
}

// Wr1 [512][64] -> fragment order: frag=(lvl,ks,ntile) 4*4*4=64 frags of 512.
__global__ void k_convR(const float* __restrict__ Wr1, unsigned short* __restrict__ Wr1tF) {
    int i = blockIdx.x * 256 + threadIdx.x;              // 32768
    int frag = i >> 9, within = i & 511;
    int lvl = frag >> 4, ks = (frag >> 2) & 3, ntile = frag & 3;
    int lane = within >> 3, j = within & 7;
    int q = lane >> 4, l16 = lane & 15;
    int n = ntile * 16 + l16;
    int k = lvl * 128 + ks * 32 + q * 8 + j;
    Wr1tF[i] = f2bf(Wr1[k * 64 + n]);
}

// h0 = node_emb[atom_type] (fp32 + bf16 copies)
__global__ void k_embed(const int* __restrict__ atom_type,
                        const float* __restrict__ node_emb,
                        float* __restrict__ h0, unsigned short* __restrict__ hb0) {
    int i = blockIdx.x * blockDim.x + threadIdx.x;
    if (i >= N_NODES * DIM) return;
    int n = i >> 7, d = i & 127;
    float v = node_emb[atom_type[n] * DIM + d];
    h0[i] = v;
    hb0[i] = f2bf(v);
}

// ---------------- CSR build (once per call) ----------------

__global__ void k_hist(const int* __restrict__ dst, int* __restrict__ counts) {
    int e = blockIdx.x * blockDim.x + threadIdx.x;
    if (e >= N_EDGES) return;
    atomicAdd(&counts[dst[e]], 1);
}

__global__ void k_bsum(const int* __restrict__ counts, int* __restrict__ bsums) {
    __shared__ int red[256];
    int c = blockIdx.x, tid = threadIdx.x;
    int base = c * CHUNK;
    int v = 0;
    for (int i = tid; i < CHUNK; i += 256)
        if (base + i < N_NODES) v += counts[base + i];
    red[tid] = v;
    __syncthreads();
    for (int s = 128; s > 0; s >>= 1) {
        if (tid < s) red[tid] += red[tid + s];
        __syncthreads();
    }
    if (tid == 0) bsums[c] = red[0];
}

__global__ void k_scan_b(int* __restrict__ bsums) {
    __shared__ int sb[NCHUNK];
    int tid = threadIdx.x;
    if (tid < NCHUNK) sb[tid] = bsums[tid];
    __syncthreads();
    if (tid == 0) {
        int run = 0;
        for (int i = 0; i < NCHUNK; ++i) { int v = sb[i]; sb[i] = run; run += v; }
    }
    __syncthreads();
    if (tid < NCHUNK) bsums[tid] = sb[tid];
}

__global__ void k_scan_final(const int* __restrict__ counts, const int* __restrict__ bsums,
                             int* __restrict__ offsets) {
    __shared__ int sc[CHUNK];
    int c = blockIdx.x, tid = threadIdx.x;
    int base = c * CHUNK;
    for (int i = tid; i < CHUNK; i += 256)
        sc[i] = (base + i < N_NODES) ? counts[base + i] : 0;
    __syncthreads();
    if (tid == 0) {
        int run = bsums[c];
        for (int i = 0; i < CHUNK; ++i) { int v = sc[i]; sc[i] = run; run += v; }
    }
    __syncthreads();
    for (int i = tid; i < CHUNK; i += 256)
        if (base + i < N_NODES) offsets[base + i] = sc[i];
    if (c == 0 && tid == 0) offsets[N_NODES] = N_EDGES;
}

// Fill perm-ordered meta: one uint2 per edge = (src, bin<<16 | w_fixed16).
__global__ void k_fill(const int* __restrict__ src, const int* __restrict__ dst,
                       const float* __restrict__ dist,
                       const int* __restrict__ offsets, int* __restrict__ cnt2,
                       uint2* __restrict__ meta) {
    int e = blockIdx.x * blockDim.x + threadIdx.x;
    if (e >= N_EDGES) return;
    int d = dst[e];
    int pos = offsets[d] + atomicAdd(&cnt2[d], 1);
    float x = dist[e];
    float p = x * ((float)NBINS / 10.0f);
    int bin = (int)p;
    if (bin > NBINS - 1) bin = NBINS - 1;
    float w = p - (float)bin;
    int wq = (int)(w * 65535.0f + 0.5f);
    if (wq > 65535) wq = 65535;
    meta[pos] = make_uint2((unsigned)src[e], ((unsigned)bin << 16) | (unsigned)wq);
}

// ---------------- per-layer kernels ----------------

// Tabulate edge MLP on NBINS+1 bins -> bf16 table.
__global__ void k_table(const float* __restrict__ Wc1, const float* __restrict__ bc1,
                        const float* __restrict__ Wc2, const float* __restrict__ bc2,
                        const float* __restrict__ Wc3, const float* __restrict__ bc3,
                        unsigned short* __restrict__ tableb) {
    __shared__ float t[DIM];
    __shared__ float u[DIM];
    int b = blockIdx.x;
    int d = threadIdx.x;
    float dist = (float)b * (10.0f / (float)NBINS);
    const float gap = 10.0f / 29.0f;
    float acc = bc1[d];
#pragma unroll
    for (int k = 0; k < RBF_R; ++k) {
        float c = (float)k * (10.0f / 29.0f);
        float df = dist - c;
        acc += expf(-df * df / gap) * Wc1[k * DIM + d];
    }
    t[d] = sp05(acc);
    __syncthreads();
    acc = bc2[d];
#pragma unroll 8
    for (int k = 0; k < DIM; ++k) acc += t[k] * Wc2[k * DIM + d];
    u[d] = acc;
    __syncthreads();
    acc = bc3[d];
#pragma unroll 8
    for (int k = 0; k < DIM; ++k) acc += u[k] * Wc3[k * DIM + d];
    tableb[b * DIM + d] = f2bf(acc);
}

// Pack (a, delta) per bin/dim into one uint: lo=a, hi=table[bin+1]-table[bin].
__global__ void k_pack(const unsigned short* __restrict__ tableb,
                       unsigned int* __restrict__ packed) {
    int i = blockIdx.x * 256 + threadIdx.x;   // NBINS*128
    float a = bf2f(tableb[i]);
    float b = bf2f(tableb[i + DIM]);
    packed[i] = (unsigned int)f2bf(a) | ((unsigned int)f2bf(b - a) << 16);
}

// MFMA GEMM: Cb = bf16( Ab @ W^T + bias + 1 ). Fragment-order B.
__global__ __launch_bounds__(256) void k_gemm_g(const unsigned short* __restrict__ Ab,
                                                const unsigned short* __restrict__ WtF,
                                                const float* __restrict__ bias,
                                                unsigned short* __restrict__ Cb) {
    int tid = threadIdx.x;
    int wave = tid >> 6, lane = tid & 63;
    int q = lane >> 4, l16 = lane & 15;
    int mhalf = wave & 1, nhalf = wave >> 1;
    int rb = blockIdx.x * 64 + mhalf * 32;
    int c0 = nhalf * 64;
    bf16x8 bfrag[4][4];
#pragma unroll
    for (int ks = 0; ks < 4; ++ks)
#pragma unroll
        for (int nt = 0; nt < 4; ++nt)
            bfrag[ks][nt] = *(const bf16x8*)&WtF[(size_t)(ks * 8 + nhalf * 4 + nt) * 512 + lane * 8];
    f32x4 acc[2][4] = {};
#pragma unroll
    for (int ks = 0; ks < 4; ++ks)
#pragma unroll
        for (int mt = 0; mt < 2; ++mt) {
            int m = rb + mt * 16 + l16;
            if (m > N_NODES - 1) m = N_NODES - 1;
            bf16x8 a = *(const bf16x8*)&Ab[(size_t)m * 128 + ks * 32 + q * 8];
#pragma unroll
            for (int nt = 0; nt < 4; ++nt)
                acc[mt][nt] = __builtin_amdgcn_mfma_f32_16x16x32_bf16(a, bfrag[ks][nt], acc[mt][nt], 0, 0, 0);
        }
#pragma unroll
    for (int mt = 0; mt < 2; ++mt)
#pragma unroll
        for (int nt = 0; nt < 4; ++nt) {
            int col = c0 + nt * 16 + l16;
            float b = bias[col] + 1.0f;
#pragma unroll
            for (int r = 0; r < 4; ++r) {
                int row = rb + mt * 16 + q * 4 + r;
                if (row < N_NODES) Cb[(size_t)row * 128 + col] = f2bf(acc[mt][nt][r] + b);
            }
        }
}

// Gather: wave-per-node (4 nodes / 256-block). Lane owns dims {2*lane, 2*lane+1}.
// One uint2 broadcast meta load per edge; 4-edge unroll for MLP.
__global__ __launch_bounds__(256) void k_gather(
    const int* __restrict__ offsets, const uint2* __restrict__ meta,
    const unsigned int* __restrict__ packed, const unsigned short* __restrict__ gb,
    unsigned short* __restrict__ nodeb) {
    int wave = threadIdx.x >> 6, lane = threadIdx.x & 63;
    int n = blockIdx.x * 4 + wave;
    int beg = offsets[n], end = offsets[n + 1];
    int off = lane * 2;
    const float ws = 1.0f / 65535.0f;
    float acc0 = 0.f, acc1 = 0.f, acc2 = 0.f, acc3 = 0.f;
    int j = beg;
    for (; j + 4 <= end; j += 4) {
        uint2 m0 = meta[j], m1 = meta[j + 1], m2 = meta[j + 2], m3 = meta[j + 3];
        uint2 p0 = *(const uint2*)&packed[(size_t)(m0.y >> 16) * DIM + off];
        uint2 p1 = *(const uint2*)&packed[(size_t)(m1.y >> 16) * DIM + off];
        uint2 p2 = *(const uint2*)&packed[(size_t)(m2.y >> 16) * DIM + off];
        uint2 p3 = *(const uint2*)&packed[(size_t)(m3.y >> 16) * DIM + off];
        unsigned int g0 = *(const unsigned int*)&gb[(size_t)m0.x * DIM + off];
        unsigned int g1 = *(const unsigned int*)&gb[(size_t)m1.x * DIM + off];
        unsigned int g2 = *(const unsigned int*)&gb[(size_t)m2.x * DIM + off];
        unsigned int g3 = *(const unsigned int*)&gb[(size_t)m3.x * DIM + off];
        float w0 = (float)(m0.y & 0xffff) * ws;
        float w1 = (float)(m1.y & 0xffff) * ws;
        float w2 = (float)(m2.y & 0xffff) * ws;
        float w3 = (float)(m3.y & 0xffff) * ws;
        acc0 += bf2f(g0 & 0xffff) * (bf2f(p0.x & 0xffff) + w0 * bf2f(p0.x >> 16));
        acc1 += bf2f(g0 >> 16)    * (bf2f(p0.y & 0xffff) + w0 * bf2f(p0.y >> 16));
        acc2 += bf2f(g1 & 0xffff) * (bf2f(p1.x & 0xffff) + w1 * bf2f(p1.x >> 16));
        acc3 += bf2f(g1 >> 16)    * (bf2f(p1.y & 0xffff) + w1 * bf2f(p1.y >> 16));
        acc0 += bf2f(g2 & 0xffff) * (bf2f(p2.x & 0xffff) + w2 * bf2f(p2.x >> 16));
        acc1 += bf2f(g2 >> 16)    * (bf2f(p2.y & 0xffff) + w2 * bf2f(p2.y >> 16));
        acc2 += bf2f(g3 & 0xffff) * (bf2f(p3.x & 0xffff) + w3 * bf2f(p3.x >> 16));
        acc3 += bf2f(g3 >> 16)    * (bf2f(p3.y & 0xffff) + w3 * bf2f(p3.y >> 16));
    }
    for (; j < end; ++j) {
        uint2 m0 = meta[j];
        uint2 p0 = *(const uint2*)&packed[(size_t)(m0.y >> 16) * DIM + off];
        unsigned int g0 = *(const unsigned int*)&gb[(size_t)m0.x * DIM + off];
        float w0 = (float)(m0.y & 0xffff) * ws;
        acc0 += bf2f(g0 & 0xffff) * (bf2f(p0.x & 0xffff) + w0 * bf2f(p0.x >> 16));
        acc1 += bf2f(g0 >> 16)    * (bf2f(p0.y & 0xffff) + w0 * bf2f(p0.y >> 16));
    }
    acc0 += acc2; acc1 += acc3;
    unsigned int o = (unsigned int)f2bf(acc0) | ((unsigned int)f2bf(acc1) << 16);
    *(unsigned int*)&nodeb[(size_t)n * DIM + off] = o;
}

// h_out = h_in + sp05(nodeb@W2^T + b2) @ W3^T + b3 ; fp32 + bf16 outputs.
__global__ __launch_bounds__(256) void k_node_update(
    const unsigned short* __restrict__ nodeb,
    const unsigned short* __restrict__ W2tF, const float* __restrict__ b2,
    const unsigned short* __restrict__ W3tF, const float* __restrict__ b3,
    const float* __restrict__ h_in, float* __restrict__ h_out,
    unsigned short* __restrict__ hb_out) {
    __shared__ unsigned short ts[64][136];
    int tid = threadIdx.x;
    int wave = tid >> 6, lane = tid & 63;
    int q = lane >> 4, l16 = lane & 15;
    int mhalf = wave & 1, nhalf = wave >> 1;
    int rb = blockIdx.x * 64 + mhalf * 32;
    int c0 = nhalf * 64;

    bf16x8 bfrag[4][4];
#pragma unroll
    for (int ks = 0; ks < 4; ++ks)
#pragma unroll
        for (int nt = 0; nt < 4; ++nt)
            bfrag[ks][nt] = *(const bf16x8*)&W2tF[(size_t)(ks * 8 + nhalf * 4 + nt) * 512 + lane * 8];
    f32x4 acc[2][4] = {};
#pragma unroll
    for (int ks = 0; ks < 4; ++ks)
#pragma unroll
        for (int mt = 0; mt < 2; ++mt) {
            int m = rb + mt * 16 + l16;
            if (m > N_NODES - 1) m = N_NODES - 1;
            bf16x8 a = *(const bf16x8*)&nodeb[(size_t)m * 128 + ks * 32 + q * 8];
#pragma unroll
            for (int nt = 0; nt < 4; ++nt)
                acc[mt][nt] = __builtin_amdgcn_mfma_f32_16x16x32_bf16(a, bfrag[ks][nt], acc[mt][nt], 0, 0, 0);
        }
#pragma unroll
    for (int mt = 0; mt < 2; ++mt)
#pragma unroll
        for (int nt = 0; nt < 4; ++nt) {
            int col = c0 + nt * 16 + l16;
            float b = b2[col];
#pragma unroll
            for (int r = 0; r < 4; ++r) {
                int lrow = mhalf * 32 + mt * 16 + q * 4 + r;
                ts[lrow][col] = f2bf(sp05(acc[mt][nt][r] + b));
            }
        }
    __syncthreads();
#pragma unroll
    for (int ks = 0; ks < 4; ++ks)
#pragma unroll
        for (int nt = 0; nt < 4; ++nt)
            bfrag[ks][nt] = *(const bf16x8*)&W3tF[(size_t)(ks * 8 + nhalf * 4 + nt) * 512 + lane * 8];
#pragma unroll
    for (int mt = 0; mt < 2; ++mt)
#pragma unroll
        for (int nt = 0; nt < 4; ++nt) acc[mt][nt] = (f32x4){0.f, 0.f, 0.f, 0.f};
#pragma unroll
    for (int ks = 0; ks < 4; ++ks)
#pragma unroll
        for (int mt = 0; mt < 2; ++mt) {
            int lrow = mhalf * 32 + mt * 16 + l16;
            bf16x8 a = *(const bf16x8*)&ts[lrow][ks * 32 + q * 8];
#pragma unroll
            for (int nt = 0; nt < 4; ++nt)
                acc[mt][nt] = __builtin_amdgcn_mfma_f32_16x16x32_bf16(a, bfrag[ks][nt], acc[mt][nt], 0, 0, 0);
        }
#pragma unroll
    for (int mt = 0; mt < 2; ++mt)
#pragma unroll
        for (int nt = 0; nt < 4; ++nt) {
            int col = c0 + nt * 16 + l16;
            float b = b3[col];
#pragma unroll
            for (int r = 0; r < 4; ++r) {
                int row = rb + mt * 16 + q * 4 + r;
                if (row < N_NODES) {
                    size_t idx = (size_t)row * 128 + col;
                    float v = h_in[idx] + acc[mt][nt][r] + b;
                    h_out[idx] = v;
                    hb_out[idx] = f2bf(v);
                }
            }
        }
}

// Readout: 128 rows/block, Wr1 staged in LDS (64 KB) so B-reads are ds_read_b128.
__global__ __launch_bounds__(256) void k_readout(
    const unsigned short* __restrict__ hb0, const unsigned short* __restrict__ hb1,
    const unsigned short* __restrict__ hb2, const unsigned short* __restrict__ hb3,
    const unsigned short* __restrict__ Wr1tF, const float* __restrict__ br1,
    const float* __restrict__ Wr2, const float* __restrict__ br2,
    const int* __restrict__ graph_ids, float* __restrict__ out) {
    __shared__ uint4 sB4[4096];   // 64 KB: all of Wr1tF in fragment order
    int tid = threadIdx.x;
    const uint4* wsrc = (const uint4*)Wr1tF;
    for (int i = tid; i < 4096; i += 256) sB4[i] = wsrc[i];
    __syncthreads();
    const unsigned short* sB = (const unsigned short*)sB4;
    int wave = tid >> 6, lane = tid & 63;
    int q = lane >> 4, l16 = lane & 15;
    int rb0 = blockIdx.x * 128 + wave * 16;   // m-tile mt at rb0 + mt*64
    const unsigned short* hbs[4] = {hb0, hb1, hb2, hb3};
    f32x4 acc[2][4] = {};
    for (int lvl = 0; lvl < 4; ++lvl) {
        bf16x8 bf[4][4];
#pragma unroll
        for (int ks = 0; ks < 4; ++ks)
#pragma unroll
            for (int nt = 0; nt < 4; ++nt)
                bf[ks][nt] = *(const bf16x8*)&sB[(size_t)((lvl * 4 + ks) * 4 + nt) * 512 + lane * 8];
        const unsigned short* Ab = hbs[lvl];
        bf16x8 a[2][4];
#pragma unroll
        for (int mt = 0; mt < 2; ++mt)
#pragma unroll
            for (int ks = 0; ks < 4; ++ks) {
                int m = rb0 + mt * 64 + l16;
                if (m > N_NODES - 1) m = N_NODES - 1;
                a[mt][ks] = *(const bf16x8*)&Ab[(size_t)m * 128 + ks * 32 + q * 8];
            }
#pragma unroll
        for (int ks = 0; ks < 4; ++ks)
#pragma unroll
            for (int mt = 0; mt < 2; ++mt)
#pragma unroll
                for (int nt = 0; nt < 4; ++nt)
                    acc[mt][nt] = __builtin_amdgcn_mfma_f32_16x16x32_bf16(a[mt][ks], bf[ks][nt], acc[mt][nt], 0, 0, 0);
    }
    float brr = br2[0];
#pragma unroll
    for (int mt = 0; mt < 2; ++mt) {
        float partial[4] = {0.f, 0.f, 0.f, 0.f};
#pragma unroll
        for (int nt = 0; nt < 4; ++nt) {
            int col = nt * 16 + l16;
            float b = br1[col];
            float w = Wr2[col];
#pragma unroll
            for (int r = 0; r < 4; ++r) partial[r] += sp1(acc[mt][nt][r] + b) * w;
        }
#pragma unroll
        for (int r = 0; r < 4; ++r) {
            float v = partial[r];
            v += __shfl_xor(v, 1); v += __shfl_xor(v, 2);
            v += __shfl_xor(v, 4); v += __shfl_xor(v, 8);
            if (l16 == 0) {
                int row = rb0 + mt * 64 + q * 4 + r;
                if (row < N_NODES) atomicAdd(&out[graph_ids[row]], v + brr);
            }
        }
    }
}

extern "C" void kernel_launch(void* const* d_in, const int* in_sizes, int n_in,
                              void* d_out, int out_size, void* d_ws, size_t ws_size,
                              hipStream_t stream) {
    const int* atom_type   = (const int*)d_in[0];
    const int* src         = (const int*)d_in[1];
    const int* dst         = (const int*)d_in[2];
    const int* graph_ids   = (const int*)d_in[3];
    const float* dist      = (const float*)d_in[4];
    const float* node_emb  = (const float*)d_in[5];
    const float* W_n1 = (const float*)d_in[6];  const float* b_n1 = (const float*)d_in[7];
    const float* W_c1 = (const float*)d_in[8];  const float* b_c1 = (const float*)d_in[9];
    const float* W_c2 = (const float*)d_in[10]; const float* b_c2 = (const float*)d_in[11];
    const float* W_c3 = (const float*)d_in[12]; const float* b_c3 = (const float*)d_in[13];
    const float* W_n2 = (const float*)d_in[14]; const float* b_n2 = (const float*)d_in[15];
    const float* W_n3 = (const float*)d_in[16]; const float* b_n3 = (const float*)d_in[17];
    const float* W_r1 = (const float*)d_in[18]; const float* b_r1 = (const float*)d_in[19];
    const float* W_r2 = (const float*)d_in[20]; const float* b_r2 = (const float*)d_in[21];
    float* out = (float*)d_out;

    size_t ND = (size_t)N_NODES * DIM;   // 7,680,000
    // float region
    float* h_even = (float*)d_ws;
    float* h_odd  = h_even + ND;
    // uint2 meta (8-B aligned: 2*ND*4 bytes offset is divisible by 8)
    uint2* meta   = (uint2*)(h_odd + ND);               // N_EDGES
    // int region
    int* offsets  = (int*)(meta + N_EDGES);             // 60008 (padded)
    int* counts   = offsets + 60008;                    // 60000
    int* cnt2     = counts + N_NODES;                   // 60000
    int* bsums    = cnt2 + N_NODES;                     // 128 (padded)
    unsigned int* packed = (unsigned int*)(bsums + 128);  // NBINS*128 uints
    // ushort region
    unsigned short* hb0    = (unsigned short*)(packed + (size_t)NBINS * DIM);
    unsigned short* hb1    = hb0 + ND;
    unsigned short* hb2    = hb1 + ND;
    unsigned short* hb3    = hb2 + ND;
    unsigned short* gb     = hb3 + ND;
    unsigned short* nodeb  = gb + ND;
    unsigned short* tableb = nodeb + ND;                // (NBINS+1)*128
    unsigned short* WtF    = tableb + (size_t)(NBINS + 1) * DIM;  // 9*16384
    unsigned short* Wr1tF  = WtF + 9 * 16384;           // 32768

    unsigned short* hbp[4] = {hb0, hb1, hb2, hb3};
    float* hcur = h_even;
    float* hnext = h_odd;

    hipMemsetAsync(out, 0, B_GRAPHS * sizeof(float), stream);
    hipMemsetAsync(counts, 0, (2 * N_NODES + 128) * sizeof(int), stream);

    k_convW<<<(9 * 16384) / 256, 256, 0, stream>>>(W_n1, W_n2, W_n3, WtF);
    k_convR<<<32768 / 256, 256, 0, stream>>>(W_r1, Wr1tF);
    k_embed<<<(N_NODES * DIM) / 256, 256, 0, stream>>>(atom_type, node_emb, h_even, hb0);

    // CSR build (dst-sorted edge meta)
    k_hist<<<(N_EDGES + 255) / 256, 256, 0, stream>>>(dst, counts);
    k_bsum<<<NCHUNK, 256, 0, stream>>>(counts, bsums);
    k_scan_b<<<1, 128, 0, stream>>>(bsums);
    k_scan_final<<<NCHUNK, 256, 0, stream>>>(counts, bsums, offsets);
    k_fill<<<(N_EDGES + 255) / 256, 256, 0, stream>>>(src, dst, dist, offsets, cnt2, meta);

    int gblocks = (N_NODES + 63) / 64;      // 938
    int rblocks = (N_NODES + 127) / 128;    // 469
    for (int i = 0; i < NLAYERS; ++i) {
        k_table<<<NBINS + 1, DIM, 0, stream>>>(
            W_c1 + (size_t)i * RBF_R * DIM, b_c1 + (size_t)i * DIM,
            W_c2 + (size_t)i * DIM * DIM,  b_c2 + (size_t)i * DIM,
            W_c3 + (size_t)i * DIM * DIM,  b_c3 + (size_t)i * DIM, tableb);
        k_pack<<<(NBINS * DIM) / 256, 256, 0, stream>>>(tableb, packed);
        k_gemm_g<<<gblocks, 256, 0, stream>>>(
            hbp[i], WtF + (size_t)i * 16384, b_n1 + (size_t)i * DIM, gb);
        k_gather<<<N_NODES / 4, 256, 0, stream>>>(offsets, meta, packed, gb, nodeb);
        k_node_update<<<gblocks, 256, 0, stream>>>(
            nodeb, WtF + (size_t)(3 + i) * 16384, b_n2 + (size_t)i * DIM,
            WtF + (size_t)(6 + i) * 16384, b_n3 + (size_t)i * DIM,
            hcur, hnext, hbp[i + 1]);
        float* tmp = hcur; hcur = hnext; hnext = tmp;
    }
    k_readout<<<rblocks, 256, 0, stream>>>(
        hb0, hb1, hb2, hb3, Wr1tF, b_r1, W_r2, b_r2, graph_ids, out);
}